// Round 8
// baseline (2131.342 us; speedup 1.0000x reference)
//
#include <hip/hip_runtime.h>
#include <hip/hip_bf16.h>
#include <stdint.h>

// SAGE (GraphSAGE, LSTM aggregator). f32 I/O, bf16 MFMA internally.
// N=30000, DMAX=16, dims 128 -> 256 -> 64.
// R13 -> R14 (R13: 1025us best; rec2 602us, FETCH 1.75GB = 524MB xg gathers +
// ~1.2GB Whh2 L2-miss refetch (4.2MB/step/XCD of dead xg2 lines thrash the
// 4MB L2). 92K cyc/CU-step vs ~5K pipe work -> bound by scattered-128B HBM
// path, not any pipe. The xg2 table costs 2048B/node/step because the slice
// spans all 1024 gate-cols; the raw h1 row is only 512B):
//   1. KILL xg tables (R8 fusion, done right): per block-step, COOPERATIVELY
//      stage the 64 neighbor rows (32KB) into LDS s_x (R8 failed by per-lane
//      scattered A-frags x8 waves = 3.94GB issued; one shared stage fixes it).
//      Passes compute gates = s_x@Wih^T + s_h@Whh^T + bias via MFMA (128/pass,
//      2x R13 -- cheap at 9.4% MfmaUtil). Gather stream 524->131MB; per-XCD
//      pollution 1MB/step -> Wih+Whh (1MB) stay L2-resident -> 1.2GB refetch
//      gone. xg_gemm dispatches + tables deleted; +cvt_feat (~10us).
//   2. T14 async stage: issue step-t+1 row loads into regs BEFORE step t's
//      passes, ds_write after the barrier -> HBM latency hidden under MFMAs.
//   3. Numerics = R8's (f32-accumulated gate-init; R8 passed same absmax).
// Verified layouts (learn_hip m89/m91): A[m=lane&15][k=q*8+j],
// D[row=q*4+r][col=lane&15]; W[4F,F] row-major == gemm-BT B-frag layout.

#define NN 30000
#define DMAXX 16

typedef __bf16 bf16_t;
typedef __bf16 bf16x8 __attribute__((ext_vector_type(8)));
typedef float f32x4 __attribute__((ext_vector_type(4)));

// persistent scratch (fully rewritten every call; no cross-call state reuse)
__device__ __align__(16) bf16_t g_hbuf[(size_t)NN * 256];    // layer-1 output h1
__device__ __align__(16) bf16_t g_fbuf[(size_t)NN * 128];    // bf16 copy of feat
__device__ __align__(16) bf16_t g_wbuf[753664];              // bf16 weight copies
__device__ int g_perm[NN];                                   // degree-sorted node ids

#define OFF_WIH1 0
#define OFF_WHH1 65536
#define OFF_WSELF1 131072
#define OFF_WNEIGH1 163840
#define OFF_WIH2 196608
#define OFF_WHH2 458752
#define OFF_WSELF2 720896
#define OFF_WNEIGH2 737280
#define W_TOTAL 753664

__global__ __launch_bounds__(256)
void cvt_weights(const float* __restrict__ s0, const float* __restrict__ s1,
                 const float* __restrict__ s2, const float* __restrict__ s3,
                 const float* __restrict__ s4, const float* __restrict__ s5,
                 const float* __restrict__ s6, const float* __restrict__ s7)
{
    int i = (blockIdx.x * 256 + threadIdx.x) * 4;
    if (i >= W_TOTAL) return;
    const float* src; int off;
    if      (i < OFF_WHH1)   { src = s0; off = OFF_WIH1; }
    else if (i < OFF_WSELF1) { src = s1; off = OFF_WHH1; }
    else if (i < OFF_WNEIGH1){ src = s2; off = OFF_WSELF1; }
    else if (i < OFF_WIH2)   { src = s3; off = OFF_WNEIGH1; }
    else if (i < OFF_WHH2)   { src = s4; off = OFF_WIH2; }
    else if (i < OFF_WSELF2) { src = s5; off = OFF_WHH2; }
    else if (i < OFF_WNEIGH2){ src = s6; off = OFF_WSELF2; }
    else                     { src = s7; off = OFF_WNEIGH2; }
    float4 v = *reinterpret_cast<const float4*>(src + (i - off));
    bf16_t o[4] __attribute__((aligned(8)));
    o[0] = (bf16_t)v.x; o[1] = (bf16_t)v.y; o[2] = (bf16_t)v.z; o[3] = (bf16_t)v.w;
    *reinterpret_cast<uint2*>(&g_wbuf[i]) = *reinterpret_cast<const uint2*>(o);
}

// feat f32 -> bf16 table (same rounding as the old stage_tile XF32 path)
__global__ __launch_bounds__(256)
void cvt_feat(const float* __restrict__ src, bf16_t* __restrict__ dst)
{
    int i = (blockIdx.x * 256 + threadIdx.x) * 8;   // grid covers NN*128 exactly
    float4 f0 = *reinterpret_cast<const float4*>(src + i);
    float4 f1 = *reinterpret_cast<const float4*>(src + i + 4);
    bf16_t t[8] __attribute__((aligned(16)));
    t[0]=(bf16_t)f0.x; t[1]=(bf16_t)f0.y; t[2]=(bf16_t)f0.z; t[3]=(bf16_t)f0.w;
    t[4]=(bf16_t)f1.x; t[5]=(bf16_t)f1.y; t[6]=(bf16_t)f1.z; t[7]=(bf16_t)f1.w;
    *reinterpret_cast<uint4*>(&dst[i]) = *reinterpret_cast<const uint4*>(t);
}

// counting sort of node ids by DESCENDING degree (LPT block scheduling).
__global__ __launch_bounds__(256)
void build_perm(const int* __restrict__ deg, int* __restrict__ perm)
{
    __shared__ int s_base[DMAXX + 1];
    const int tid = threadIdx.x;
    if (tid <= DMAXX) s_base[tid] = 0;
    __syncthreads();
    for (int i = tid; i < NN; i += 256) {
        int d = deg[i]; d = d < 0 ? 0 : (d > DMAXX ? DMAXX : d);
        atomicAdd(&s_base[d], 1);
    }
    __syncthreads();
    if (tid == 0) {
        int acc = 0;
        for (int d = DMAXX; d >= 0; --d) { int c = s_base[d]; s_base[d] = acc; acc += c; }
    }
    __syncthreads();
    for (int i = tid; i < NN; i += 256) {
        int d = deg[i]; d = d < 0 ? 0 : (d > DMAXX ? DMAXX : d);
        int p = atomicAdd(&s_base[d], 1);
        perm[p] = i;
    }
}

__device__ __forceinline__ float fsig(float x) { return 1.0f / (1.0f + __expf(-x)); }
__device__ __forceinline__ float ftanh(float x) { return 1.0f - 2.0f / (__expf(2.0f * x) + 1.0f); }

// stage a 64-row bf16 x-tile with per-row node ids (from LDS array) into LDS
template<int F, int LDA, int NT>
__device__ __forceinline__ void stage_rows(bf16_t* dst, const bf16_t* src, const int* nodes, int tid)
{
    constexpr int UN = F / 8;
    for (int e = tid; e < 64 * UN; e += NT) {
        int m = e / UN, sub = e - m * UN;
        int row = nodes[m];
        const bf16_t* p = src + (size_t)row * F + sub * 8;
        *reinterpret_cast<uint4*>(&dst[m * LDA + sub * 8]) = *reinterpret_cast<const uint4*>(p);
    }
}

// LSTM recurrence with fused gate-init GEMM + fused fc epilogue.
// Block b: nodes perm[b*64 .. b*64+63] (degree-sorted DESC), loops to
// tmax = max(deg in block). 16 waves = NWR row-groups x NWC col-waves.
// Per step: cooperative stage of 64 neighbor rows into s_x (T14 async:
// loads issued one step early), then passes compute
//   gates = s_x @ Wih^T + s_h @ Whh^T + (bih+bhh)   [all-MFMA, f32 acc]
// out = x_self@Wself^T + h_fin@Wneigh^T + bout
template<int F, int OUTF, bool RELU, typename OutT>
__global__ __launch_bounds__(1024, 4)
void sage_rec(const bf16_t* __restrict__ xself,   // [NN,F] bf16 (self rows)
              const bf16_t* __restrict__ xnbr,    // [NN,F] bf16 (gather rows)
              const int* __restrict__ nbr_idx, const int* __restrict__ deg,
              const int* __restrict__ perm,
              const bf16_t* __restrict__ Wih, const bf16_t* __restrict__ Whh,
              const float* __restrict__ bih, const float* __restrict__ bhh,
              const bf16_t* __restrict__ Wself, const bf16_t* __restrict__ Wneigh,
              const float* __restrict__ bout, OutT* __restrict__ outp)
{
    constexpr int M = 64, LDA = F + 8, KK = F / 32, NW = 16, NT = 1024;
    constexpr int NWC = F / 16;            // col-waves, 16 cols each
    constexpr int NWR = NW / NWC;          // row-groups (1 for F=256, 2 for F=128)
    constexpr int RT = M / (16 * NWR);     // row-tiles per wave (4 or 2)
    constexpr int NPASS = RT / 2;          // 2 row-tiles per pass
    constexpr int UNX = F / 8;             // 16B units per row
    constexpr int NPF = (M * UNX) / NT;    // stage loads per thread (1 or 2)
    static_assert(NWC * NWR == NW && RT % 2 == 0 && (M * UNX) % NT == 0, "");
    const int tid = threadIdx.x, wave = tid >> 6, lane = tid & 63;
    const int q = lane >> 4, m16 = lane & 15;
    const int wc = wave % NWC, wr = wave / NWC;
    const int ROWB = wr * (RT * 16);       // this wave's row base in tile
    const int col = wc * 16 + m16;         // this lane's output column (per gate)
    const int slot0 = blockIdx.x * M;

    __shared__ __align__(16) bf16_t s_h[2][M * LDA];   // double-buffered h
    __shared__ __align__(16) bf16_t s_x[M * LDA];      // staged neighbor rows
    __shared__ int s_idx[M * DMAXX];
    __shared__ int s_deg[M];
    __shared__ int s_node[M];
    __shared__ int s_tmax;

    for (int i = tid; i < M; i += NT) {
        int slot = slot0 + i; if (slot >= NN) slot = NN - 1;
        int node = perm[slot];
        s_node[i] = node;
        s_deg[i] = deg[node];
    }
    __syncthreads();
    for (int i = tid; i < M * DMAXX; i += NT) {
        int node = s_node[i >> 4];
        int v = nbr_idx[node * DMAXX + (i & 15)];
        if (v < 0) v = 0; if (v >= NN) v = NN - 1;
        s_idx[i] = v;
    }
    for (int i = tid; i < M * LDA; i += NT) s_h[0][i] = (bf16_t)0.0f;
    if (tid == 0) {
        int mx = 1;
        for (int i = 0; i < M; ++i) { int d = s_deg[i]; mx = d > mx ? d : mx; }
        s_tmax = mx;
    }
    __syncthreads();
    const int tmax = s_tmax;   // uniform-degree blocks: ~= block's degree bucket

    // gate bias (bih+bhh) for this lane's column, per gate
    float bias4[4];
    #pragma unroll
    for (int g = 0; g < 4; ++g) bias4[g] = bih[g * F + col] + bhh[g * F + col];

    // stage helpers (T14 split: load-to-regs early / ds_write late)
    auto ld_nbr = [&](int t, uint4* pf) {
        #pragma unroll
        for (int i = 0; i < NPF; ++i) {
            int e = tid + i * NT;
            int m = e / UNX, sub = e - m * UNX;
            int row = s_idx[m * DMAXX + t];
            pf[i] = *reinterpret_cast<const uint4*>(xnbr + (size_t)row * F + sub * 8);
        }
    };
    auto st_nbr = [&](const uint4* pf) {
        #pragma unroll
        for (int i = 0; i < NPF; ++i) {
            int e = tid + i * NT;
            int m = e / UNX, sub = e - m * UNX;
            *reinterpret_cast<uint4*>(&s_x[m * LDA + sub * 8]) = pf[i];
        }
    };

    // persistent cell state: one f32x4 per row-tile (constexpr-indexed only)
    f32x4 c0, c1, c2, c3;
    #pragma unroll
    for (int r = 0; r < 4; ++r) { c0[r]=0.f; c1[r]=0.f; c2[r]=0.f; c3[r]=0.f; }

    // one pass: 2 row-tiles x 4 gates x this wave's 16 cols, ih+hh fused MFMA
    auto do_pass = [&](int rtb, f32x4& cA, f32x4& cB,
                       const bf16_t* cur, bf16_t* nxt, int t) {
        f32x4 acc[2][4];
        #pragma unroll
        for (int j = 0; j < 2; ++j)
            #pragma unroll
            for (int g = 0; g < 4; ++g)
                #pragma unroll
                for (int r = 0; r < 4; ++r) acc[j][g][r] = bias4[g];
        #pragma unroll
        for (int kk = 0; kk < KK; ++kk) {
            const int ko = kk * 32 + q * 8;
            bf16x8 ax0 = *reinterpret_cast<const bf16x8*>(
                &s_x[(ROWB + rtb * 16 + m16) * LDA + ko]);
            bf16x8 ax1 = *reinterpret_cast<const bf16x8*>(
                &s_x[(ROWB + (rtb + 1) * 16 + m16) * LDA + ko]);
            bf16x8 ah0 = *reinterpret_cast<const bf16x8*>(
                &cur[(ROWB + rtb * 16 + m16) * LDA + ko]);
            bf16x8 ah1 = *reinterpret_cast<const bf16x8*>(
                &cur[(ROWB + (rtb + 1) * 16 + m16) * LDA + ko]);
            #pragma unroll
            for (int g = 0; g < 4; ++g) {
                bf16x8 bi = *reinterpret_cast<const bf16x8*>(
                    Wih + (size_t)(g * F + col) * F + ko);
                bf16x8 bh = *reinterpret_cast<const bf16x8*>(
                    Whh + (size_t)(g * F + col) * F + ko);
                acc[0][g] = __builtin_amdgcn_mfma_f32_16x16x32_bf16(ax0, bi, acc[0][g], 0, 0, 0);
                acc[1][g] = __builtin_amdgcn_mfma_f32_16x16x32_bf16(ax1, bi, acc[1][g], 0, 0, 0);
                acc[0][g] = __builtin_amdgcn_mfma_f32_16x16x32_bf16(ah0, bh, acc[0][g], 0, 0, 0);
                acc[1][g] = __builtin_amdgcn_mfma_f32_16x16x32_bf16(ah1, bh, acc[1][g], 0, 0, 0);
            }
        }
        // pointwise LSTM update + masked store:
        //   t <  deg : write h_new (and update c)
        //   t == deg : copy frozen h from cur (this thread's t-1 write)
        //   t >  deg : skip -- nxt already holds the frozen value
        #pragma unroll
        for (int j = 0; j < 2; ++j) {
            f32x4& cc = j ? cB : cA;
            #pragma unroll
            for (int r = 0; r < 4; ++r) {
                int rowr = ROWB + (rtb + j) * 16 + q * 4 + r;
                float iv = fsig (acc[j][0][r]);
                float fv = fsig (acc[j][1][r]);
                float gv = ftanh(acc[j][2][r]);
                float ov = fsig (acc[j][3][r]);
                float cn = fv * cc[r] + iv * gv;
                float hv = ov * ftanh(cn);
                const int pos = rowr * LDA + col;
                int d = s_deg[rowr];
                if (t < d) {
                    cc[r] = cn;
                    nxt[pos] = (bf16_t)hv;
                } else if (t == d) {
                    reinterpret_cast<unsigned short*>(nxt)[pos] =
                        reinterpret_cast<const unsigned short*>(cur)[pos];
                }
            }
        }
    };

    // prologue: stage s_x for t=0
    {
        uint4 pf[NPF];
        ld_nbr(0, pf);
        st_nbr(pf);
    }
    __syncthreads();

    #pragma unroll 1
    for (int t = 0; t < tmax; ++t) {
        const bf16_t* cur = s_h[t & 1];
        bf16_t* nxt = s_h[(t + 1) & 1];
        // T14: issue next step's row loads now; latency hides under passes
        uint4 pf[NPF];
        const bool havepf = (t + 1 < tmax);
        if (havepf) ld_nbr(t + 1, pf);
        do_pass(0, c0, c1, cur, nxt, t);
        if constexpr (NPASS > 1) {
            __builtin_amdgcn_sched_barrier(0);   // keep passes sequential (reg pressure)
            do_pass(2, c2, c3, cur, nxt, t);
        }
        __syncthreads();   // nxt fully written; s_x fully consumed
        if (havepf) {
            st_nbr(pf);
            __syncthreads();   // s_x ready for step t+1
        }
    }

    // final h is in s_h[tmax&1]; stage self-rows into the other buffer
    const int fb = tmax & 1;
    const bf16_t* hfin = s_h[fb];
    bf16_t* hstage = s_h[fb ^ 1];
    stage_rows<F, LDA, NT>(hstage, xself, s_node, tid);
    __syncthreads();

    // epilogue: out = x_self @ Wself^T + h_fin @ Wneigh^T + bout (+relu)
    constexpr int NCT = OUTF / 16;
    constexpr int TILES = NCT * 4;     // 4 row-tiles of the 64-node tile
    constexpr int TPW = TILES / NW;
    static_assert(TILES % NW == 0, "");
    #pragma unroll
    for (int tt = 0; tt < TPW; ++tt) {
        int tile = wave * TPW + tt;
        int ot = tile % NCT, rt = tile / NCT;
        f32x4 o;
        o[0] = 0.f; o[1] = 0.f; o[2] = 0.f; o[3] = 0.f;
        #pragma unroll
        for (int kk = 0; kk < KK; ++kk) {
            const int ko = kk * 32 + q * 8;
            bf16x8 axs = *reinterpret_cast<const bf16x8*>(&hstage[(rt * 16 + m16) * LDA + ko]);
            bf16x8 am  = *reinterpret_cast<const bf16x8*>(&hfin[(rt * 16 + m16) * LDA + ko]);
            bf16x8 bs = *reinterpret_cast<const bf16x8*>(Wself  + (size_t)(ot * 16 + m16) * F + ko);
            bf16x8 bn = *reinterpret_cast<const bf16x8*>(Wneigh + (size_t)(ot * 16 + m16) * F + ko);
            o = __builtin_amdgcn_mfma_f32_16x16x32_bf16(axs, bs, o, 0, 0, 0);
            o = __builtin_amdgcn_mfma_f32_16x16x32_bf16(am,  bn, o, 0, 0, 0);
        }
        int ocol = ot * 16 + m16;
        float bias = bout[ocol];
        #pragma unroll
        for (int r = 0; r < 4; ++r) {
            int node = s_node[rt * 16 + q * 4 + r];
            float v = o[r] + bias;
            if (RELU) v = fmaxf(v, 0.0f);
            outp[(size_t)node * OUTF + ocol] = (OutT)v;
        }
    }
}

extern "C" void kernel_launch(void* const* d_in, const int* in_sizes, int n_in,
                              void* d_out, int out_size, void* d_ws, size_t ws_size,
                              hipStream_t stream)
{
    const float* feat    = (const float*)d_in[0];
    const int*   nbr     = (const int*)d_in[1];
    const int*   degp    = (const int*)d_in[2];
    const float* Wih1    = (const float*)d_in[3];
    const float* Whh1    = (const float*)d_in[4];
    const float* bih1    = (const float*)d_in[5];
    const float* bhh1    = (const float*)d_in[6];
    const float* Wself1  = (const float*)d_in[7];
    const float* Wneigh1 = (const float*)d_in[8];
    const float* b1      = (const float*)d_in[9];
    const float* Wih2    = (const float*)d_in[10];
    const float* Whh2    = (const float*)d_in[11];
    const float* bih2    = (const float*)d_in[12];
    const float* bhh2    = (const float*)d_in[13];
    const float* Wself2  = (const float*)d_in[14];
    const float* Wneigh2 = (const float*)d_in[15];
    const float* b2      = (const float*)d_in[16];

    bf16_t *hglob, *wglob, *fglob;
    int *permg;
    hipGetSymbolAddress((void**)&hglob, HIP_SYMBOL(g_hbuf));
    hipGetSymbolAddress((void**)&wglob, HIP_SYMBOL(g_wbuf));
    hipGetSymbolAddress((void**)&fglob, HIP_SYMBOL(g_fbuf));
    hipGetSymbolAddress((void**)&permg, HIP_SYMBOL(g_perm));

    cvt_weights<<<W_TOTAL / 4 / 256, 256, 0, stream>>>(
        Wih1, Whh1, Wself1, Wneigh1, Wih2, Whh2, Wself2, Wneigh2);

    cvt_feat<<<NN * 128 / 8 / 256, 256, 0, stream>>>(feat, fglob);

    build_perm<<<1, 256, 0, stream>>>(degp, permg);

    const int grid = (NN + 63) / 64;   // 469 WGs

    sage_rec<128, 256, true, bf16_t><<<grid, 1024, 0, stream>>>(
        fglob, fglob, nbr, degp, permg,
        wglob + OFF_WIH1, wglob + OFF_WHH1, bih1, bhh1,
        wglob + OFF_WSELF1, wglob + OFF_WNEIGH1, b1, hglob);

    sage_rec<256, 64, false, float><<<grid, 1024, 0, stream>>>(
        hglob, hglob, nbr, degp, permg,
        wglob + OFF_WIH2, wglob + OFF_WHH2, bih2, bhh2,
        wglob + OFF_WSELF2, wglob + OFF_WNEIGH2, b2, (float*)d_out);
}

// Round 9
// 1107.630 us; speedup vs baseline: 1.9242x; 1.9242x over previous
//
#include <hip/hip_runtime.h>
#include <hip/hip_bf16.h>
#include <stdint.h>

// SAGE (GraphSAGE, LSTM aggregator). f32 I/O, bf16 MFMA internally.
// N=30000, DMAX=16, dims 128 -> 256 -> 64.
// R14 -> R15 (R14 FAILED 2131us: fused x@Wih streams BOTH weights -> 2MB/
// block-step issued (8GB), ~50% miss -> FETCH 4.16GB. Lesson: rec time ~=
// FETCH / 2.9TB/s; FETCH = weight_issue x miss + gathers. R13's miss cause:
// 32 blocks/XCD x 131KB dead xg2 gather lines = 4.2MB/round thrash the 4MB
// L2 between steps -> ~30% Whh miss. REVERT to R13 (proven 1025us) and
// amortize the weight stream):
//   1. F=256: ONE 4-row-tile pass (was two 2-tile passes) -> each Whh
//      B-frag loaded once per 4 A-frags. Whh issue/block-step 1MB -> 512KB
//      (4GB -> 2GB issued). Regs (R12 lesson): MFMA phase live = acc64+c16+
//      ah16 ~= 106; u[4][4] (32) loaded AFTER the MFMA chain behind
//      sched_barrier(0); 2 blk/CU x 16 waves TLP hides the gather latency.
//   2. F=128 path unchanged. Arithmetic per (row,g,kk) identical -> bit-same.
// Verified layouts (learn_hip m89/m91): A[m=lane&15][k=q*8+j],
// D[row=q*4+r][col=lane&15]; W[4F,F] row-major == gemm-BT B-frag layout.

#define NN 30000
#define DMAXX 16

typedef __bf16 bf16_t;
typedef __bf16 bf16x8 __attribute__((ext_vector_type(8)));
typedef float f32x4 __attribute__((ext_vector_type(4)));
typedef unsigned short u16x4 __attribute__((ext_vector_type(4)));

// persistent scratch (fully rewritten every call; no cross-call state reuse)
__device__ __align__(16) bf16_t g_hbuf[(size_t)NN * 256];    // layer-1 output h1
__device__ __align__(16) bf16_t g_xg1[(size_t)NN * 512];     // feat@Wih1^T + biases
__device__ __align__(16) bf16_t g_xg2[(size_t)NN * 1024];    // h1@Wih2^T + biases
__device__ __align__(16) bf16_t g_wbuf[753664];              // bf16 weight copies
__device__ int g_perm[NN];                                   // degree-sorted node ids

#define OFF_WIH1 0
#define OFF_WHH1 65536
#define OFF_WSELF1 131072
#define OFF_WNEIGH1 163840
#define OFF_WIH2 196608
#define OFF_WHH2 458752
#define OFF_WSELF2 720896
#define OFF_WNEIGH2 737280
#define W_TOTAL 753664

__global__ __launch_bounds__(256)
void cvt_weights(const float* __restrict__ s0, const float* __restrict__ s1,
                 const float* __restrict__ s2, const float* __restrict__ s3,
                 const float* __restrict__ s4, const float* __restrict__ s5,
                 const float* __restrict__ s6, const float* __restrict__ s7)
{
    int i = (blockIdx.x * 256 + threadIdx.x) * 4;
    if (i >= W_TOTAL) return;
    const float* src; int off;
    if      (i < OFF_WHH1)   { src = s0; off = OFF_WIH1; }
    else if (i < OFF_WSELF1) { src = s1; off = OFF_WHH1; }
    else if (i < OFF_WNEIGH1){ src = s2; off = OFF_WSELF1; }
    else if (i < OFF_WIH2)   { src = s3; off = OFF_WNEIGH1; }
    else if (i < OFF_WHH2)   { src = s4; off = OFF_WIH2; }
    else if (i < OFF_WSELF2) { src = s5; off = OFF_WHH2; }
    else if (i < OFF_WNEIGH2){ src = s6; off = OFF_WSELF2; }
    else                     { src = s7; off = OFF_WNEIGH2; }
    float4 v = *reinterpret_cast<const float4*>(src + (i - off));
    bf16_t o[4] __attribute__((aligned(8)));
    o[0] = (bf16_t)v.x; o[1] = (bf16_t)v.y; o[2] = (bf16_t)v.z; o[3] = (bf16_t)v.w;
    *reinterpret_cast<uint2*>(&g_wbuf[i]) = *reinterpret_cast<const uint2*>(o);
}

// counting sort of node ids by DESCENDING degree (LPT block scheduling).
__global__ __launch_bounds__(256)
void build_perm(const int* __restrict__ deg, int* __restrict__ perm)
{
    __shared__ int s_base[DMAXX + 1];
    const int tid = threadIdx.x;
    if (tid <= DMAXX) s_base[tid] = 0;
    __syncthreads();
    for (int i = tid; i < NN; i += 256) {
        int d = deg[i]; d = d < 0 ? 0 : (d > DMAXX ? DMAXX : d);
        atomicAdd(&s_base[d], 1);
    }
    __syncthreads();
    if (tid == 0) {
        int acc = 0;
        for (int d = DMAXX; d >= 0; --d) { int c = s_base[d]; s_base[d] = acc; acc += c; }
    }
    __syncthreads();
    for (int i = tid; i < NN; i += 256) {
        int d = deg[i]; d = d < 0 ? 0 : (d > DMAXX ? DMAXX : d);
        int p = atomicAdd(&s_base[d], 1);
        perm[p] = i;
    }
}

__device__ __forceinline__ float fsig(float x) { return 1.0f / (1.0f + __expf(-x)); }
__device__ __forceinline__ float ftanh(float x) { return 1.0f - 2.0f / (__expf(2.0f * x) + 1.0f); }
__device__ __forceinline__ float bf2f(unsigned short s) {
    union { unsigned u; float f; } v; v.u = ((unsigned)s) << 16; return v.f;
}

// stage a 64-row x-tile (linear rows, row-clamped) into LDS as bf16
template<int F, int LDA, int NT, bool XF32>
__device__ __forceinline__ void stage_tile(bf16_t* dst, const void* src, int row0, int tid)
{
    constexpr int UN = F / 8;          // 16B(bf16) units per row
    for (int e = tid; e < 64 * UN; e += NT) {
        int m = e / UN, sub = e - m * UN;
        int row = row0 + m; if (row >= NN) row = NN - 1;
        if constexpr (XF32) {
            const float* p = (const float*)src + (size_t)row * F + sub * 8;
            float4 f0 = reinterpret_cast<const float4*>(p)[0];
            float4 f1 = reinterpret_cast<const float4*>(p)[1];
            bf16_t t[8] __attribute__((aligned(16)));
            t[0]=(bf16_t)f0.x; t[1]=(bf16_t)f0.y; t[2]=(bf16_t)f0.z; t[3]=(bf16_t)f0.w;
            t[4]=(bf16_t)f1.x; t[5]=(bf16_t)f1.y; t[6]=(bf16_t)f1.z; t[7]=(bf16_t)f1.w;
            *reinterpret_cast<uint4*>(&dst[m * LDA + sub * 8]) = *reinterpret_cast<const uint4*>(t);
        } else {
            const bf16_t* p = (const bf16_t*)src + (size_t)row * F + sub * 8;
            *reinterpret_cast<uint4*>(&dst[m * LDA + sub * 8]) = *reinterpret_cast<const uint4*>(p);
        }
    }
}

// stage a 64-row x-tile with per-row node ids (from LDS array) into LDS
template<int F, int LDA, int NT, bool XF32>
__device__ __forceinline__ void stage_rows(bf16_t* dst, const void* src, const int* nodes, int tid)
{
    constexpr int UN = F / 8;
    for (int e = tid; e < 64 * UN; e += NT) {
        int m = e / UN, sub = e - m * UN;
        int row = nodes[m];
        if constexpr (XF32) {
            const float* p = (const float*)src + (size_t)row * F + sub * 8;
            float4 f0 = reinterpret_cast<const float4*>(p)[0];
            float4 f1 = reinterpret_cast<const float4*>(p)[1];
            bf16_t t[8] __attribute__((aligned(16)));
            t[0]=(bf16_t)f0.x; t[1]=(bf16_t)f0.y; t[2]=(bf16_t)f0.z; t[3]=(bf16_t)f0.w;
            t[4]=(bf16_t)f1.x; t[5]=(bf16_t)f1.y; t[6]=(bf16_t)f1.z; t[7]=(bf16_t)f1.w;
            *reinterpret_cast<uint4*>(&dst[m * LDA + sub * 8]) = *reinterpret_cast<const uint4*>(t);
        } else {
            const bf16_t* p = (const bf16_t*)src + (size_t)row * F + sub * 8;
            *reinterpret_cast<uint4*>(&dst[m * LDA + sub * 8]) = *reinterpret_cast<const uint4*>(p);
        }
    }
}

// xg[N, 4F] (gate-interleaved [c][g]) = x[N,F] @ W[4F,F]^T + b0 + b1
template<int F, int G, int NW, bool XF32>
__global__ __launch_bounds__(NW * 64, 2)
void xg_gemm(const void* __restrict__ xsrc_v, const bf16_t* __restrict__ W,
             const float* __restrict__ b0, const float* __restrict__ b1v,
             bf16_t* __restrict__ xg)
{
    constexpr int LDA = F + 8, KK = F / 32, NT = NW * 64;
    constexpr int CPW = G / NW;        // linear out-cols per wave
    constexpr int CT = CPW / 16;
    static_assert(CPW % 16 == 0 && F % 16 == 0, "");
    const int tid = threadIdx.x, wave = tid >> 6, lane = tid & 63;
    const int q = lane >> 4, m16 = lane & 15;
    const int row0 = blockIdx.x * 64;

    __shared__ __align__(16) bf16_t s_x[64 * LDA];
    stage_tile<F, LDA, NT, XF32>(s_x, xsrc_v, row0, tid);
    __syncthreads();

    #pragma unroll
    for (int ct = 0; ct < CT; ++ct) {
        const int lc0 = wave * CPW + ct * 16;   // linear col block (within one gate)
        const int g = lc0 / F, c0 = lc0 - g * F;
        const float bias = b0[lc0 + m16] + b1v[lc0 + m16];
        f32x4 acc[4];
        #pragma unroll
        for (int rt = 0; rt < 4; ++rt)
            #pragma unroll
            for (int r = 0; r < 4; ++r) acc[rt][r] = bias;
        #pragma unroll
        for (int kk = 0; kk < KK; ++kk) {
            const int ko = kk * 32 + q * 8;
            bf16x8 b = *reinterpret_cast<const bf16x8*>(W + (size_t)(lc0 + m16) * F + ko);
            #pragma unroll
            for (int rt = 0; rt < 4; ++rt) {
                bf16x8 a = *reinterpret_cast<const bf16x8*>(&s_x[(rt * 16 + m16) * LDA + ko]);
                acc[rt] = __builtin_amdgcn_mfma_f32_16x16x32_bf16(a, b, acc[rt], 0, 0, 0);
            }
        }
        #pragma unroll
        for (int rt = 0; rt < 4; ++rt)
            #pragma unroll
            for (int r = 0; r < 4; ++r) {
                int row = row0 + rt * 16 + q * 4 + r;
                if (row < NN)
                    xg[(size_t)row * G + (size_t)(c0 + m16) * 4 + g] = (bf16_t)acc[rt][r];
            }
    }
}

// LSTM recurrence over gathered neighbors + fused fc epilogue.
// Block b: nodes perm[b*64 .. b*64+63] (degree-sorted DESC), loops to
// tmax = max(deg in block). 16 waves = NWR row-groups x NWC col-waves.
// F=256: ONE 4-row-tile pass per step (Whh B-frag loaded once per 4 A-frags);
// F=128: one 2-row-tile pass (unchanged from R13).
// gates = gather(xg) + h @ Whh^T ; out = x_self@Wself^T + h_fin@Wneigh^T + b
template<int F, int OUTF, bool RELU, bool XF32, typename OutT>
__global__ __launch_bounds__(1024, 4)
void sage_rec(const void* __restrict__ xself_v,
              const bf16_t* __restrict__ xg,
              const int* __restrict__ nbr_idx, const int* __restrict__ deg,
              const int* __restrict__ perm,
              const bf16_t* __restrict__ Whh,
              const bf16_t* __restrict__ Wself, const bf16_t* __restrict__ Wneigh,
              const float* __restrict__ bout, OutT* __restrict__ outp)
{
    constexpr int M = 64, LDA = F + 8, KK = F / 32, NW = 16, NT = 1024;
    constexpr int NWC = F / 16;            // col-waves, 16 cols each
    constexpr int NWR = NW / NWC;          // row-groups (1 for F=256, 2 for F=128)
    constexpr int RT = M / (16 * NWR);     // row-tiles per wave (4 or 2)
    constexpr int G4 = 4 * F;
    static_assert(NWC * NWR == NW && (RT == 2 || RT == 4), "");
    const int tid = threadIdx.x, wave = tid >> 6, lane = tid & 63;
    const int q = lane >> 4, m16 = lane & 15;
    const int wc = wave % NWC, wr = wave / NWC;
    const int ROWB = wr * (RT * 16);       // this wave's row base in tile
    const int col = wc * 16 + m16;         // this lane's output column (per gate)
    const int slot0 = blockIdx.x * M;

    __shared__ __align__(16) bf16_t s_h[2][M * LDA];   // double-buffered h
    __shared__ int s_idx[M * DMAXX];
    __shared__ int s_deg[M];
    __shared__ int s_node[M];
    __shared__ int s_tmax;

    for (int i = tid; i < M; i += NT) {
        int slot = slot0 + i; if (slot >= NN) slot = NN - 1;
        int node = perm[slot];
        s_node[i] = node;
        s_deg[i] = deg[node];
    }
    __syncthreads();
    for (int i = tid; i < M * DMAXX; i += NT) {
        int node = s_node[i >> 4];
        int v = nbr_idx[node * DMAXX + (i & 15)];
        if (v < 0) v = 0; if (v >= NN) v = NN - 1;
        s_idx[i] = v;
    }
    for (int i = tid; i < M * LDA; i += NT) s_h[0][i] = (bf16_t)0.0f;
    if (tid == 0) {
        int mx = 1;
        for (int i = 0; i < M; ++i) { int d = s_deg[i]; mx = d > mx ? d : mx; }
        s_tmax = mx;
    }
    __syncthreads();
    const int tmax = s_tmax;   // uniform-degree blocks: ~= block's degree bucket

    // persistent cell state: one f32x4 per row-tile (named, never runtime-indexed)
    f32x4 c0, c1, c2, c3;
    #pragma unroll
    for (int r = 0; r < 4; ++r) { c0[r]=0.f; c1[r]=0.f; c2[r]=0.f; c3[r]=0.f; }

    // pointwise LSTM update + masked store for one row-tile:
    //   t <  deg : write h_new (and update c)
    //   t == deg : copy frozen h from cur (this thread's t-1 write)
    //   t >  deg : skip -- nxt already holds the frozen value
    auto pointwise = [&](int rtile, f32x4& cc, const f32x4* accg, const u16x4* uu,
                         const bf16_t* cur, bf16_t* nxt, int t) {
        #pragma unroll
        for (int r = 0; r < 4; ++r) {
            int rowr = ROWB + rtile * 16 + q * 4 + r;
            float iv = fsig (accg[0][r] + bf2f(uu[r].x));
            float fv = fsig (accg[1][r] + bf2f(uu[r].y));
            float gv = ftanh(accg[2][r] + bf2f(uu[r].z));
            float ov = fsig (accg[3][r] + bf2f(uu[r].w));
            float cn = fv * cc[r] + iv * gv;
            float hv = ov * ftanh(cn);
            const int pos = rowr * LDA + col;
            int d = s_deg[rowr];
            if (t < d) {
                cc[r] = cn;
                nxt[pos] = (bf16_t)hv;
            } else if (t == d) {
                reinterpret_cast<unsigned short*>(nxt)[pos] =
                    reinterpret_cast<const unsigned short*>(cur)[pos];
            }
        }
    };

    // F=128 path: one pass of 2 row-tiles (R13-identical)
    auto do_pass2 = [&](const bf16_t* cur, bf16_t* nxt, int t) {
        u16x4 u[2][4];
        #pragma unroll
        for (int j = 0; j < 2; ++j)
            #pragma unroll
            for (int r = 0; r < 4; ++r) {
                int row = s_idx[(ROWB + j * 16 + q * 4 + r) * DMAXX + t];
                u[j][r] = *reinterpret_cast<const u16x4*>(
                    xg + (size_t)row * G4 + (size_t)col * 4);
            }
        f32x4 acc[2][4];
        #pragma unroll
        for (int j = 0; j < 2; ++j)
            #pragma unroll
            for (int g = 0; g < 4; ++g)
                #pragma unroll
                for (int r = 0; r < 4; ++r) acc[j][g][r] = 0.0f;
        #pragma unroll
        for (int kk = 0; kk < KK; ++kk) {
            const int ko = kk * 32 + q * 8;
            bf16x8 ah0 = *reinterpret_cast<const bf16x8*>(&cur[(ROWB + m16) * LDA + ko]);
            bf16x8 ah1 = *reinterpret_cast<const bf16x8*>(&cur[(ROWB + 16 + m16) * LDA + ko]);
            #pragma unroll
            for (int g = 0; g < 4; ++g) {
                bf16x8 bh = *reinterpret_cast<const bf16x8*>(
                    Whh + (size_t)(g * F + col) * F + ko);
                acc[0][g] = __builtin_amdgcn_mfma_f32_16x16x32_bf16(ah0, bh, acc[0][g], 0, 0, 0);
                acc[1][g] = __builtin_amdgcn_mfma_f32_16x16x32_bf16(ah1, bh, acc[1][g], 0, 0, 0);
            }
        }
        pointwise(0, c0, acc[0], u[0], cur, nxt, t);
        pointwise(1, c1, acc[1], u[1], cur, nxt, t);
    };

    // F=256 path: ONE pass of 4 row-tiles -- each Whh B-frag feeds 4 MFMAs.
    // u loads deferred to AFTER the MFMA chain (sched_barrier fence) to keep
    // MFMA-phase live regs ~106 (acc64+c16+ah16+addr) -> no spill at 16 waves.
    auto do_pass4 = [&](const bf16_t* cur, bf16_t* nxt, int t) {
        f32x4 acc[4][4];
        #pragma unroll
        for (int j = 0; j < 4; ++j)
            #pragma unroll
            for (int g = 0; g < 4; ++g)
                #pragma unroll
                for (int r = 0; r < 4; ++r) acc[j][g][r] = 0.0f;
        #pragma unroll
        for (int kk = 0; kk < KK; ++kk) {
            const int ko = kk * 32 + q * 8;
            bf16x8 a0 = *reinterpret_cast<const bf16x8*>(&cur[(m16) * LDA + ko]);
            bf16x8 a1 = *reinterpret_cast<const bf16x8*>(&cur[(16 + m16) * LDA + ko]);
            bf16x8 a2 = *reinterpret_cast<const bf16x8*>(&cur[(32 + m16) * LDA + ko]);
            bf16x8 a3 = *reinterpret_cast<const bf16x8*>(&cur[(48 + m16) * LDA + ko]);
            #pragma unroll
            for (int g = 0; g < 4; ++g) {
                bf16x8 bh = *reinterpret_cast<const bf16x8*>(
                    Whh + (size_t)(g * F + col) * F + ko);
                acc[0][g] = __builtin_amdgcn_mfma_f32_16x16x32_bf16(a0, bh, acc[0][g], 0, 0, 0);
                acc[1][g] = __builtin_amdgcn_mfma_f32_16x16x32_bf16(a1, bh, acc[1][g], 0, 0, 0);
                acc[2][g] = __builtin_amdgcn_mfma_f32_16x16x32_bf16(a2, bh, acc[2][g], 0, 0, 0);
                acc[3][g] = __builtin_amdgcn_mfma_f32_16x16x32_bf16(a3, bh, acc[3][g], 0, 0, 0);
            }
        }
        __builtin_amdgcn_sched_barrier(0);   // fence: keep u loads out of MFMA phase
        u16x4 u[4][4];
        #pragma unroll
        for (int j = 0; j < 4; ++j)
            #pragma unroll
            for (int r = 0; r < 4; ++r) {
                int row = s_idx[(j * 16 + q * 4 + r) * DMAXX + t];
                u[j][r] = *reinterpret_cast<const u16x4*>(
                    xg + (size_t)row * G4 + (size_t)col * 4);
            }
        pointwise(0, c0, acc[0], u[0], cur, nxt, t);
        pointwise(1, c1, acc[1], u[1], cur, nxt, t);
        pointwise(2, c2, acc[2], u[2], cur, nxt, t);
        pointwise(3, c3, acc[3], u[3], cur, nxt, t);
    };

    #pragma unroll 1
    for (int t = 0; t < tmax; ++t) {
        const bf16_t* cur = s_h[t & 1];
        bf16_t* nxt = s_h[(t + 1) & 1];
        if constexpr (RT == 4) {
            do_pass4(cur, nxt, t);
        } else {
            do_pass2(cur, nxt, t);
        }
        __syncthreads();   // nxt fully written; cur fully consumed
    }

    // final h is in s_h[tmax&1]; stage self-rows into the other buffer
    const int fb = tmax & 1;
    const bf16_t* hfin = s_h[fb];
    bf16_t* hstage = s_h[fb ^ 1];
    stage_rows<F, LDA, NT, XF32>(hstage, xself_v, s_node, tid);
    __syncthreads();

    // epilogue: out = x_self @ Wself^T + h_fin @ Wneigh^T + bout (+relu)
    constexpr int NCT = OUTF / 16;
    constexpr int TILES = NCT * 4;     // 4 row-tiles of the 64-node tile
    constexpr int TPW = TILES / NW;
    static_assert(TILES % NW == 0, "");
    #pragma unroll
    for (int tt = 0; tt < TPW; ++tt) {
        int tile = wave * TPW + tt;
        int ot = tile % NCT, rt = tile / NCT;
        f32x4 o;
        o[0] = 0.f; o[1] = 0.f; o[2] = 0.f; o[3] = 0.f;
        #pragma unroll
        for (int kk = 0; kk < KK; ++kk) {
            const int ko = kk * 32 + q * 8;
            bf16x8 axs = *reinterpret_cast<const bf16x8*>(&hstage[(rt * 16 + m16) * LDA + ko]);
            bf16x8 am  = *reinterpret_cast<const bf16x8*>(&hfin[(rt * 16 + m16) * LDA + ko]);
            bf16x8 bs = *reinterpret_cast<const bf16x8*>(Wself  + (size_t)(ot * 16 + m16) * F + ko);
            bf16x8 bn = *reinterpret_cast<const bf16x8*>(Wneigh + (size_t)(ot * 16 + m16) * F + ko);
            o = __builtin_amdgcn_mfma_f32_16x16x32_bf16(axs, bs, o, 0, 0, 0);
            o = __builtin_amdgcn_mfma_f32_16x16x32_bf16(am,  bn, o, 0, 0, 0);
        }
        int ocol = ot * 16 + m16;
        float bias = bout[ocol];
        #pragma unroll
        for (int r = 0; r < 4; ++r) {
            int node = s_node[rt * 16 + q * 4 + r];
            float v = o[r] + bias;
            if (RELU) v = fmaxf(v, 0.0f);
            outp[(size_t)node * OUTF + ocol] = (OutT)v;
        }
    }
}

extern "C" void kernel_launch(void* const* d_in, const int* in_sizes, int n_in,
                              void* d_out, int out_size, void* d_ws, size_t ws_size,
                              hipStream_t stream)
{
    const float* feat    = (const float*)d_in[0];
    const int*   nbr     = (const int*)d_in[1];
    const int*   degp    = (const int*)d_in[2];
    const float* Wih1    = (const float*)d_in[3];
    const float* Whh1    = (const float*)d_in[4];
    const float* bih1    = (const float*)d_in[5];
    const float* bhh1    = (const float*)d_in[6];
    const float* Wself1  = (const float*)d_in[7];
    const float* Wneigh1 = (const float*)d_in[8];
    const float* b1      = (const float*)d_in[9];
    const float* Wih2    = (const float*)d_in[10];
    const float* Whh2    = (const float*)d_in[11];
    const float* bih2    = (const float*)d_in[12];
    const float* bhh2    = (const float*)d_in[13];
    const float* Wself2  = (const float*)d_in[14];
    const float* Wneigh2 = (const float*)d_in[15];
    const float* b2      = (const float*)d_in[16];

    bf16_t *hglob, *wglob, *xg1, *xg2;
    int *permg;
    hipGetSymbolAddress((void**)&hglob, HIP_SYMBOL(g_hbuf));
    hipGetSymbolAddress((void**)&wglob, HIP_SYMBOL(g_wbuf));
    hipGetSymbolAddress((void**)&xg1,   HIP_SYMBOL(g_xg1));
    hipGetSymbolAddress((void**)&xg2,   HIP_SYMBOL(g_xg2));
    hipGetSymbolAddress((void**)&permg, HIP_SYMBOL(g_perm));

    cvt_weights<<<W_TOTAL / 4 / 256, 256, 0, stream>>>(
        Wih1, Whh1, Wself1, Wneigh1, Wih2, Whh2, Wself2, Wneigh2);

    build_perm<<<1, 256, 0, stream>>>(degp, permg);

    const int grid = (NN + 63) / 64;   // 469 WGs

    xg_gemm<128, 512, 8, true><<<grid, 512, 0, stream>>>(
        feat, wglob + OFF_WIH1, bih1, bhh1, xg1);

    sage_rec<128, 256, true, true, bf16_t><<<grid, 1024, 0, stream>>>(
        feat, xg1, nbr, degp, permg, wglob + OFF_WHH1,
        wglob + OFF_WSELF1, wglob + OFF_WNEIGH1, b1, hglob);

    xg_gemm<256, 1024, 8, false><<<grid, 512, 0, stream>>>(
        hglob, wglob + OFF_WIH2, bih2, bhh2, xg2);

    sage_rec<256, 64, false, false, float><<<grid, 1024, 0, stream>>>(
        hglob, xg2, nbr, degp, permg, wglob + OFF_WHH2,
        wglob + OFF_WSELF2, wglob + OFF_WNEIGH2, b2, (float*)d_out);
}

// Round 10
// 1098.886 us; speedup vs baseline: 1.9395x; 1.0080x over previous
//
#include <hip/hip_runtime.h>
#include <hip/hip_bf16.h>
#include <stdint.h>

// SAGE (GraphSAGE, LSTM aggregator). f32 I/O, bf16 MFMA internally.
// N=30000, DMAX=16, dims 128 -> 256 -> 64.
// R15 -> R16 (R15: 1107us. Whh-amortization real (FETCH 1.705->1.570e6) but
// spills RETURNED: WRITE 192->478MB. The deferred u[4][4] (32 regs) + c(16)
// + temps all live at once in the 64-arch half after the MFMA chain -> spill.
// Confirmed model: rec2 dur = hbm_bytes / ~3.1 TB/s exactly; spill bytes
// count. Fix the spill, keep the 4-tile pass):
//   1. do_pass4: u loads PER ROW-TILE, double-buffered (uA/uB = 8+8 regs);
//      tile j+1's gather issues during tile j's pointwise; sched_barrier(0)
//      after each pointwise fences the regions so loads can't be hoisted
//      together. Worst arch live ~56 < 64 -> no spill.
//   2. Everything else identical to R15 (which is R13 + 4-tile pass).
// Verified layouts (learn_hip m89/m91): A[m=lane&15][k=q*8+j],
// D[row=q*4+r][col=lane&15]; W[4F,F] row-major == gemm-BT B-frag layout.

#define NN 30000
#define DMAXX 16

typedef __bf16 bf16_t;
typedef __bf16 bf16x8 __attribute__((ext_vector_type(8)));
typedef float f32x4 __attribute__((ext_vector_type(4)));
typedef unsigned short u16x4 __attribute__((ext_vector_type(4)));

// persistent scratch (fully rewritten every call; no cross-call state reuse)
__device__ __align__(16) bf16_t g_hbuf[(size_t)NN * 256];    // layer-1 output h1
__device__ __align__(16) bf16_t g_xg1[(size_t)NN * 512];     // feat@Wih1^T + biases
__device__ __align__(16) bf16_t g_xg2[(size_t)NN * 1024];    // h1@Wih2^T + biases
__device__ __align__(16) bf16_t g_wbuf[753664];              // bf16 weight copies
__device__ int g_perm[NN];                                   // degree-sorted node ids

#define OFF_WIH1 0
#define OFF_WHH1 65536
#define OFF_WSELF1 131072
#define OFF_WNEIGH1 163840
#define OFF_WIH2 196608
#define OFF_WHH2 458752
#define OFF_WSELF2 720896
#define OFF_WNEIGH2 737280
#define W_TOTAL 753664

__global__ __launch_bounds__(256)
void cvt_weights(const float* __restrict__ s0, const float* __restrict__ s1,
                 const float* __restrict__ s2, const float* __restrict__ s3,
                 const float* __restrict__ s4, const float* __restrict__ s5,
                 const float* __restrict__ s6, const float* __restrict__ s7)
{
    int i = (blockIdx.x * 256 + threadIdx.x) * 4;
    if (i >= W_TOTAL) return;
    const float* src; int off;
    if      (i < OFF_WHH1)   { src = s0; off = OFF_WIH1; }
    else if (i < OFF_WSELF1) { src = s1; off = OFF_WHH1; }
    else if (i < OFF_WNEIGH1){ src = s2; off = OFF_WSELF1; }
    else if (i < OFF_WIH2)   { src = s3; off = OFF_WNEIGH1; }
    else if (i < OFF_WHH2)   { src = s4; off = OFF_WIH2; }
    else if (i < OFF_WSELF2) { src = s5; off = OFF_WHH2; }
    else if (i < OFF_WNEIGH2){ src = s6; off = OFF_WSELF2; }
    else                     { src = s7; off = OFF_WNEIGH2; }
    float4 v = *reinterpret_cast<const float4*>(src + (i - off));
    bf16_t o[4] __attribute__((aligned(8)));
    o[0] = (bf16_t)v.x; o[1] = (bf16_t)v.y; o[2] = (bf16_t)v.z; o[3] = (bf16_t)v.w;
    *reinterpret_cast<uint2*>(&g_wbuf[i]) = *reinterpret_cast<const uint2*>(o);
}

// counting sort of node ids by DESCENDING degree (LPT block scheduling).
__global__ __launch_bounds__(256)
void build_perm(const int* __restrict__ deg, int* __restrict__ perm)
{
    __shared__ int s_base[DMAXX + 1];
    const int tid = threadIdx.x;
    if (tid <= DMAXX) s_base[tid] = 0;
    __syncthreads();
    for (int i = tid; i < NN; i += 256) {
        int d = deg[i]; d = d < 0 ? 0 : (d > DMAXX ? DMAXX : d);
        atomicAdd(&s_base[d], 1);
    }
    __syncthreads();
    if (tid == 0) {
        int acc = 0;
        for (int d = DMAXX; d >= 0; --d) { int c = s_base[d]; s_base[d] = acc; acc += c; }
    }
    __syncthreads();
    for (int i = tid; i < NN; i += 256) {
        int d = deg[i]; d = d < 0 ? 0 : (d > DMAXX ? DMAXX : d);
        int p = atomicAdd(&s_base[d], 1);
        perm[p] = i;
    }
}

__device__ __forceinline__ float fsig(float x) { return 1.0f / (1.0f + __expf(-x)); }
__device__ __forceinline__ float ftanh(float x) { return 1.0f - 2.0f / (__expf(2.0f * x) + 1.0f); }
__device__ __forceinline__ float bf2f(unsigned short s) {
    union { unsigned u; float f; } v; v.u = ((unsigned)s) << 16; return v.f;
}

// stage a 64-row x-tile (linear rows, row-clamped) into LDS as bf16
template<int F, int LDA, int NT, bool XF32>
__device__ __forceinline__ void stage_tile(bf16_t* dst, const void* src, int row0, int tid)
{
    constexpr int UN = F / 8;          // 16B(bf16) units per row
    for (int e = tid; e < 64 * UN; e += NT) {
        int m = e / UN, sub = e - m * UN;
        int row = row0 + m; if (row >= NN) row = NN - 1;
        if constexpr (XF32) {
            const float* p = (const float*)src + (size_t)row * F + sub * 8;
            float4 f0 = reinterpret_cast<const float4*>(p)[0];
            float4 f1 = reinterpret_cast<const float4*>(p)[1];
            bf16_t t[8] __attribute__((aligned(16)));
            t[0]=(bf16_t)f0.x; t[1]=(bf16_t)f0.y; t[2]=(bf16_t)f0.z; t[3]=(bf16_t)f0.w;
            t[4]=(bf16_t)f1.x; t[5]=(bf16_t)f1.y; t[6]=(bf16_t)f1.z; t[7]=(bf16_t)f1.w;
            *reinterpret_cast<uint4*>(&dst[m * LDA + sub * 8]) = *reinterpret_cast<const uint4*>(t);
        } else {
            const bf16_t* p = (const bf16_t*)src + (size_t)row * F + sub * 8;
            *reinterpret_cast<uint4*>(&dst[m * LDA + sub * 8]) = *reinterpret_cast<const uint4*>(p);
        }
    }
}

// stage a 64-row x-tile with per-row node ids (from LDS array) into LDS
template<int F, int LDA, int NT, bool XF32>
__device__ __forceinline__ void stage_rows(bf16_t* dst, const void* src, const int* nodes, int tid)
{
    constexpr int UN = F / 8;
    for (int e = tid; e < 64 * UN; e += NT) {
        int m = e / UN, sub = e - m * UN;
        int row = nodes[m];
        if constexpr (XF32) {
            const float* p = (const float*)src + (size_t)row * F + sub * 8;
            float4 f0 = reinterpret_cast<const float4*>(p)[0];
            float4 f1 = reinterpret_cast<const float4*>(p)[1];
            bf16_t t[8] __attribute__((aligned(16)));
            t[0]=(bf16_t)f0.x; t[1]=(bf16_t)f0.y; t[2]=(bf16_t)f0.z; t[3]=(bf16_t)f0.w;
            t[4]=(bf16_t)f1.x; t[5]=(bf16_t)f1.y; t[6]=(bf16_t)f1.z; t[7]=(bf16_t)f1.w;
            *reinterpret_cast<uint4*>(&dst[m * LDA + sub * 8]) = *reinterpret_cast<const uint4*>(t);
        } else {
            const bf16_t* p = (const bf16_t*)src + (size_t)row * F + sub * 8;
            *reinterpret_cast<uint4*>(&dst[m * LDA + sub * 8]) = *reinterpret_cast<const uint4*>(p);
        }
    }
}

// xg[N, 4F] (gate-interleaved [c][g]) = x[N,F] @ W[4F,F]^T + b0 + b1
template<int F, int G, int NW, bool XF32>
__global__ __launch_bounds__(NW * 64, 2)
void xg_gemm(const void* __restrict__ xsrc_v, const bf16_t* __restrict__ W,
             const float* __restrict__ b0, const float* __restrict__ b1v,
             bf16_t* __restrict__ xg)
{
    constexpr int LDA = F + 8, KK = F / 32, NT = NW * 64;
    constexpr int CPW = G / NW;        // linear out-cols per wave
    constexpr int CT = CPW / 16;
    static_assert(CPW % 16 == 0 && F % 16 == 0, "");
    const int tid = threadIdx.x, wave = tid >> 6, lane = tid & 63;
    const int q = lane >> 4, m16 = lane & 15;
    const int row0 = blockIdx.x * 64;

    __shared__ __align__(16) bf16_t s_x[64 * LDA];
    stage_tile<F, LDA, NT, XF32>(s_x, xsrc_v, row0, tid);
    __syncthreads();

    #pragma unroll
    for (int ct = 0; ct < CT; ++ct) {
        const int lc0 = wave * CPW + ct * 16;   // linear col block (within one gate)
        const int g = lc0 / F, c0 = lc0 - g * F;
        const float bias = b0[lc0 + m16] + b1v[lc0 + m16];
        f32x4 acc[4];
        #pragma unroll
        for (int rt = 0; rt < 4; ++rt)
            #pragma unroll
            for (int r = 0; r < 4; ++r) acc[rt][r] = bias;
        #pragma unroll
        for (int kk = 0; kk < KK; ++kk) {
            const int ko = kk * 32 + q * 8;
            bf16x8 b = *reinterpret_cast<const bf16x8*>(W + (size_t)(lc0 + m16) * F + ko);
            #pragma unroll
            for (int rt = 0; rt < 4; ++rt) {
                bf16x8 a = *reinterpret_cast<const bf16x8*>(&s_x[(rt * 16 + m16) * LDA + ko]);
                acc[rt] = __builtin_amdgcn_mfma_f32_16x16x32_bf16(a, b, acc[rt], 0, 0, 0);
            }
        }
        #pragma unroll
        for (int rt = 0; rt < 4; ++rt)
            #pragma unroll
            for (int r = 0; r < 4; ++r) {
                int row = row0 + rt * 16 + q * 4 + r;
                if (row < NN)
                    xg[(size_t)row * G + (size_t)(c0 + m16) * 4 + g] = (bf16_t)acc[rt][r];
            }
    }
}

// LSTM recurrence over gathered neighbors + fused fc epilogue.
// Block b: nodes perm[b*64 .. b*64+63] (degree-sorted DESC), loops to
// tmax = max(deg in block). 16 waves = NWR row-groups x NWC col-waves.
// F=256: ONE 4-row-tile pass per step (Whh B-frag loaded once per 4 A-frags),
//        u gathers pipelined per row-tile (uA/uB) to stay spill-free;
// F=128: one 2-row-tile pass (R13-identical).
// gates = gather(xg) + h @ Whh^T ; out = x_self@Wself^T + h_fin@Wneigh^T + b
template<int F, int OUTF, bool RELU, bool XF32, typename OutT>
__global__ __launch_bounds__(1024, 4)
void sage_rec(const void* __restrict__ xself_v,
              const bf16_t* __restrict__ xg,
              const int* __restrict__ nbr_idx, const int* __restrict__ deg,
              const int* __restrict__ perm,
              const bf16_t* __restrict__ Whh,
              const bf16_t* __restrict__ Wself, const bf16_t* __restrict__ Wneigh,
              const float* __restrict__ bout, OutT* __restrict__ outp)
{
    constexpr int M = 64, LDA = F + 8, KK = F / 32, NW = 16, NT = 1024;
    constexpr int NWC = F / 16;            // col-waves, 16 cols each
    constexpr int NWR = NW / NWC;          // row-groups (1 for F=256, 2 for F=128)
    constexpr int RT = M / (16 * NWR);     // row-tiles per wave (4 or 2)
    constexpr int G4 = 4 * F;
    static_assert(NWC * NWR == NW && (RT == 2 || RT == 4), "");
    const int tid = threadIdx.x, wave = tid >> 6, lane = tid & 63;
    const int q = lane >> 4, m16 = lane & 15;
    const int wc = wave % NWC, wr = wave / NWC;
    const int ROWB = wr * (RT * 16);       // this wave's row base in tile
    const int col = wc * 16 + m16;         // this lane's output column (per gate)
    const int slot0 = blockIdx.x * M;

    __shared__ __align__(16) bf16_t s_h[2][M * LDA];   // double-buffered h
    __shared__ int s_idx[M * DMAXX];
    __shared__ int s_deg[M];
    __shared__ int s_node[M];
    __shared__ int s_tmax;

    for (int i = tid; i < M; i += NT) {
        int slot = slot0 + i; if (slot >= NN) slot = NN - 1;
        int node = perm[slot];
        s_node[i] = node;
        s_deg[i] = deg[node];
    }
    __syncthreads();
    for (int i = tid; i < M * DMAXX; i += NT) {
        int node = s_node[i >> 4];
        int v = nbr_idx[node * DMAXX + (i & 15)];
        if (v < 0) v = 0; if (v >= NN) v = NN - 1;
        s_idx[i] = v;
    }
    for (int i = tid; i < M * LDA; i += NT) s_h[0][i] = (bf16_t)0.0f;
    if (tid == 0) {
        int mx = 1;
        for (int i = 0; i < M; ++i) { int d = s_deg[i]; mx = d > mx ? d : mx; }
        s_tmax = mx;
    }
    __syncthreads();
    const int tmax = s_tmax;   // uniform-degree blocks: ~= block's degree bucket

    // persistent cell state: one f32x4 per row-tile (named, never runtime-indexed)
    f32x4 c0, c1, c2, c3;
    #pragma unroll
    for (int r = 0; r < 4; ++r) { c0[r]=0.f; c1[r]=0.f; c2[r]=0.f; c3[r]=0.f; }

    // pointwise LSTM update + masked store for one row-tile:
    //   t <  deg : write h_new (and update c)
    //   t == deg : copy frozen h from cur (this thread's t-1 write)
    //   t >  deg : skip -- nxt already holds the frozen value
    auto pointwise = [&](int rtile, f32x4& cc, const f32x4* accg, const u16x4* uu,
                         const bf16_t* cur, bf16_t* nxt, int t) {
        #pragma unroll
        for (int r = 0; r < 4; ++r) {
            int rowr = ROWB + rtile * 16 + q * 4 + r;
            float iv = fsig (accg[0][r] + bf2f(uu[r].x));
            float fv = fsig (accg[1][r] + bf2f(uu[r].y));
            float gv = ftanh(accg[2][r] + bf2f(uu[r].z));
            float ov = fsig (accg[3][r] + bf2f(uu[r].w));
            float cn = fv * cc[r] + iv * gv;
            float hv = ov * ftanh(cn);
            const int pos = rowr * LDA + col;
            int d = s_deg[rowr];
            if (t < d) {
                cc[r] = cn;
                nxt[pos] = (bf16_t)hv;
            } else if (t == d) {
                reinterpret_cast<unsigned short*>(nxt)[pos] =
                    reinterpret_cast<const unsigned short*>(cur)[pos];
            }
        }
    };

    // gather u (xg gate-init) for one row-tile into 4 u16x4 regs
    auto ld_u = [&](int rtile, int t, u16x4* uu) {
        #pragma unroll
        for (int r = 0; r < 4; ++r) {
            int row = s_idx[(rtile * 16 + q * 4 + r) * DMAXX + t];
            uu[r] = *reinterpret_cast<const u16x4*>(
                xg + (size_t)row * G4 + (size_t)col * 4);
        }
    };

    // F=128 path: one pass of 2 row-tiles (R13-identical)
    auto do_pass2 = [&](const bf16_t* cur, bf16_t* nxt, int t) {
        u16x4 u[2][4];
        #pragma unroll
        for (int j = 0; j < 2; ++j)
            #pragma unroll
            for (int r = 0; r < 4; ++r) {
                int row = s_idx[(ROWB + j * 16 + q * 4 + r) * DMAXX + t];
                u[j][r] = *reinterpret_cast<const u16x4*>(
                    xg + (size_t)row * G4 + (size_t)col * 4);
            }
        f32x4 acc[2][4];
        #pragma unroll
        for (int j = 0; j < 2; ++j)
            #pragma unroll
            for (int g = 0; g < 4; ++g)
                #pragma unroll
                for (int r = 0; r < 4; ++r) acc[j][g][r] = 0.0f;
        #pragma unroll
        for (int kk = 0; kk < KK; ++kk) {
            const int ko = kk * 32 + q * 8;
            bf16x8 ah0 = *reinterpret_cast<const bf16x8*>(&cur[(ROWB + m16) * LDA + ko]);
            bf16x8 ah1 = *reinterpret_cast<const bf16x8*>(&cur[(ROWB + 16 + m16) * LDA + ko]);
            #pragma unroll
            for (int g = 0; g < 4; ++g) {
                bf16x8 bh = *reinterpret_cast<const bf16x8*>(
                    Whh + (size_t)(g * F + col) * F + ko);
                acc[0][g] = __builtin_amdgcn_mfma_f32_16x16x32_bf16(ah0, bh, acc[0][g], 0, 0, 0);
                acc[1][g] = __builtin_amdgcn_mfma_f32_16x16x32_bf16(ah1, bh, acc[1][g], 0, 0, 0);
            }
        }
        pointwise(0, c0, acc[0], u[0], cur, nxt, t);
        pointwise(1, c1, acc[1], u[1], cur, nxt, t);
    };

    // F=256 path: ONE pass of 4 row-tiles -- each Whh B-frag feeds 4 MFMAs.
    // u gathers pipelined per tile (uA/uB double-buffer, 16 regs max) with
    // sched_barrier(0) region fences: tile j+1's load issues during tile j's
    // pointwise; loads can't be hoisted together -> no spill.
    auto do_pass4 = [&](const bf16_t* cur, bf16_t* nxt, int t) {
        f32x4 acc[4][4];
        #pragma unroll
        for (int j = 0; j < 4; ++j)
            #pragma unroll
            for (int g = 0; g < 4; ++g)
                #pragma unroll
                for (int r = 0; r < 4; ++r) acc[j][g][r] = 0.0f;
        #pragma unroll
        for (int kk = 0; kk < KK; ++kk) {
            const int ko = kk * 32 + q * 8;
            bf16x8 a0 = *reinterpret_cast<const bf16x8*>(&cur[(m16) * LDA + ko]);
            bf16x8 a1 = *reinterpret_cast<const bf16x8*>(&cur[(16 + m16) * LDA + ko]);
            bf16x8 a2 = *reinterpret_cast<const bf16x8*>(&cur[(32 + m16) * LDA + ko]);
            bf16x8 a3 = *reinterpret_cast<const bf16x8*>(&cur[(48 + m16) * LDA + ko]);
            #pragma unroll
            for (int g = 0; g < 4; ++g) {
                bf16x8 bh = *reinterpret_cast<const bf16x8*>(
                    Whh + (size_t)(g * F + col) * F + ko);
                acc[0][g] = __builtin_amdgcn_mfma_f32_16x16x32_bf16(a0, bh, acc[0][g], 0, 0, 0);
                acc[1][g] = __builtin_amdgcn_mfma_f32_16x16x32_bf16(a1, bh, acc[1][g], 0, 0, 0);
                acc[2][g] = __builtin_amdgcn_mfma_f32_16x16x32_bf16(a2, bh, acc[2][g], 0, 0, 0);
                acc[3][g] = __builtin_amdgcn_mfma_f32_16x16x32_bf16(a3, bh, acc[3][g], 0, 0, 0);
            }
        }
        __builtin_amdgcn_sched_barrier(0);   // fence: u loads stay out of MFMA phase
        u16x4 uA[4], uB[4];
        ld_u(0, t, uA);
        #pragma unroll
        for (int j = 0; j < 4; ++j) {
            u16x4* ucur = (j & 1) ? uB : uA;
            u16x4* unxt = (j & 1) ? uA : uB;
            if (j + 1 < 4) ld_u(j + 1, t, unxt);   // hides under pointwise j
            f32x4& cc = (j == 0) ? c0 : (j == 1) ? c1 : (j == 2) ? c2 : c3;
            pointwise(j, cc, acc[j], ucur, cur, nxt, t);
            __builtin_amdgcn_sched_barrier(0);   // region fence: cap live u at 16
        }
    };

    #pragma unroll 1
    for (int t = 0; t < tmax; ++t) {
        const bf16_t* cur = s_h[t & 1];
        bf16_t* nxt = s_h[(t + 1) & 1];
        if constexpr (RT == 4) {
            do_pass4(cur, nxt, t);
        } else {
            do_pass2(cur, nxt, t);
        }
        __syncthreads();   // nxt fully written; cur fully consumed
    }

    // final h is in s_h[tmax&1]; stage self-rows into the other buffer
    const int fb = tmax & 1;
    const bf16_t* hfin = s_h[fb];
    bf16_t* hstage = s_h[fb ^ 1];
    stage_rows<F, LDA, NT, XF32>(hstage, xself_v, s_node, tid);
    __syncthreads();

    // epilogue: out = x_self @ Wself^T + h_fin @ Wneigh^T + bout (+relu)
    constexpr int NCT = OUTF / 16;
    constexpr int TILES = NCT * 4;     // 4 row-tiles of the 64-node tile
    constexpr int TPW = TILES / NW;
    static_assert(TILES % NW == 0, "");
    #pragma unroll
    for (int tt = 0; tt < TPW; ++tt) {
        int tile = wave * TPW + tt;
        int ot = tile % NCT, rt = tile / NCT;
        f32x4 o;
        o[0] = 0.f; o[1] = 0.f; o[2] = 0.f; o[3] = 0.f;
        #pragma unroll
        for (int kk = 0; kk < KK; ++kk) {
            const int ko = kk * 32 + q * 8;
            bf16x8 axs = *reinterpret_cast<const bf16x8*>(&hstage[(rt * 16 + m16) * LDA + ko]);
            bf16x8 am  = *reinterpret_cast<const bf16x8*>(&hfin[(rt * 16 + m16) * LDA + ko]);
            bf16x8 bs = *reinterpret_cast<const bf16x8*>(Wself  + (size_t)(ot * 16 + m16) * F + ko);
            bf16x8 bn = *reinterpret_cast<const bf16x8*>(Wneigh + (size_t)(ot * 16 + m16) * F + ko);
            o = __builtin_amdgcn_mfma_f32_16x16x32_bf16(axs, bs, o, 0, 0, 0);
            o = __builtin_amdgcn_mfma_f32_16x16x32_bf16(am,  bn, o, 0, 0, 0);
        }
        int ocol = ot * 16 + m16;
        float bias = bout[ocol];
        #pragma unroll
        for (int r = 0; r < 4; ++r) {
            int node = s_node[rt * 16 + q * 4 + r];
            float v = o[r] + bias;
            if (RELU) v = fmaxf(v, 0.0f);
            outp[(size_t)node * OUTF + ocol] = (OutT)v;
        }
    }
}

extern "C" void kernel_launch(void* const* d_in, const int* in_sizes, int n_in,
                              void* d_out, int out_size, void* d_ws, size_t ws_size,
                              hipStream_t stream)
{
    const float* feat    = (const float*)d_in[0];
    const int*   nbr     = (const int*)d_in[1];
    const int*   degp    = (const int*)d_in[2];
    const float* Wih1    = (const float*)d_in[3];
    const float* Whh1    = (const float*)d_in[4];
    const float* bih1    = (const float*)d_in[5];
    const float* bhh1    = (const float*)d_in[6];
    const float* Wself1  = (const float*)d_in[7];
    const float* Wneigh1 = (const float*)d_in[8];
    const float* b1      = (const float*)d_in[9];
    const float* Wih2    = (const float*)d_in[10];
    const float* Whh2    = (const float*)d_in[11];
    const float* bih2    = (const float*)d_in[12];
    const float* bhh2    = (const float*)d_in[13];
    const float* Wself2  = (const float*)d_in[14];
    const float* Wneigh2 = (const float*)d_in[15];
    const float* b2      = (const float*)d_in[16];

    bf16_t *hglob, *wglob, *xg1, *xg2;
    int *permg;
    hipGetSymbolAddress((void**)&hglob, HIP_SYMBOL(g_hbuf));
    hipGetSymbolAddress((void**)&wglob, HIP_SYMBOL(g_wbuf));
    hipGetSymbolAddress((void**)&xg1,   HIP_SYMBOL(g_xg1));
    hipGetSymbolAddress((void**)&xg2,   HIP_SYMBOL(g_xg2));
    hipGetSymbolAddress((void**)&permg, HIP_SYMBOL(g_perm));

    cvt_weights<<<W_TOTAL / 4 / 256, 256, 0, stream>>>(
        Wih1, Whh1, Wself1, Wneigh1, Wih2, Whh2, Wself2, Wneigh2);

    build_perm<<<1, 256, 0, stream>>>(degp, permg);

    const int grid = (NN + 63) / 64;   // 469 WGs

    xg_gemm<128, 512, 8, true><<<grid, 512, 0, stream>>>(
        feat, wglob + OFF_WIH1, bih1, bhh1, xg1);

    sage_rec<128, 256, true, true, bf16_t><<<grid, 1024, 0, stream>>>(
        feat, xg1, nbr, degp, permg, wglob + OFF_WHH1,
        wglob + OFF_WSELF1, wglob + OFF_WNEIGH1, b1, hglob);

    xg_gemm<256, 1024, 8, false><<<grid, 512, 0, stream>>>(
        hglob, wglob + OFF_WIH2, bih2, bhh2, xg2);

    sage_rec<256, 64, false, false, float><<<grid, 1024, 0, stream>>>(
        hglob, xg2, nbr, degp, permg, wglob + OFF_WHH2,
        wglob + OFF_WSELF2, wglob + OFF_WNEIGH2, b2, (float*)d_out);
}

// Round 11
// 1040.584 us; speedup vs baseline: 2.0482x; 1.0560x over previous
//
#include <hip/hip_runtime.h>
#include <hip/hip_bf16.h>
#include <stdint.h>

// SAGE (GraphSAGE, LSTM aggregator). f32 I/O, bf16 MFMA internally.
// N=30000, DMAX=16, dims 128 -> 256 -> 64.
// R16 -> R17 (R16: 1099us. 4-tile pass axis CLOSED: spills persist at the
// hard 128-reg/wave budget (WRITE 477MB across R15/R16). R13 (2-tile passes,
// spill-free, 1025us) is the best structure. Ledger for R13-rec2 FETCH
// 1.75GB: gathers 524MB (93% L2-miss, 61MB table vs 4MB/XCD L2) + ~1.2GB
// Whh2 L2-miss refetch caused by gather-stream eviction. rec_dur ==
// EA_bytes / 3.1TB/s on every variant -> bytes are the only lever):
//   1. Gather loads -> SYSTEM-SCOPE (__hip_atomic_load relaxed, 8B):
//      system scope bypasses L1+L2 (L2 is agent coherence point); Infinity
//      Cache is MEMORY-SIDE so it still serves these at today's rate (they
//      miss L2 anyway). L2 stays clean -> Whh ~100% hit after cold fill,
//      ~1.2GB of FETCH disappears. (R10's failed nt was an allocation HINT;
//      this is an architectural bypass.) Correctness: kernel-boundary L2
//      writeback/invalidate already guarantees xg visibility cross-XCD for
//      today's normal loads; data read is bit-identical -> absmax unchanged.
//   2. Everything else = R13 verbatim (LPT desc sort, 16-wave M=64 blocks,
//      2-tile passes, named c0..c3, sched_barrier between passes).
// Verified layouts (learn_hip m89/m91): A[m=lane&15][k=q*8+j],
// D[row=q*4+r][col=lane&15]; W[4F,F] row-major == gemm-BT B-frag layout.

#define NN 30000
#define DMAXX 16

typedef __bf16 bf16_t;
typedef __bf16 bf16x8 __attribute__((ext_vector_type(8)));
typedef float f32x4 __attribute__((ext_vector_type(4)));
typedef unsigned short u16x4 __attribute__((ext_vector_type(4)));
typedef unsigned long long u64_t;

// persistent scratch (fully rewritten every call; no cross-call state reuse)
__device__ __align__(16) bf16_t g_hbuf[(size_t)NN * 256];    // layer-1 output h1
__device__ __align__(16) bf16_t g_xg1[(size_t)NN * 512];     // feat@Wih1^T + biases
__device__ __align__(16) bf16_t g_xg2[(size_t)NN * 1024];    // h1@Wih2^T + biases
__device__ __align__(16) bf16_t g_wbuf[753664];              // bf16 weight copies
__device__ int g_perm[NN];                                   // degree-sorted node ids

#define OFF_WIH1 0
#define OFF_WHH1 65536
#define OFF_WSELF1 131072
#define OFF_WNEIGH1 163840
#define OFF_WIH2 196608
#define OFF_WHH2 458752
#define OFF_WSELF2 720896
#define OFF_WNEIGH2 737280
#define W_TOTAL 753664

__global__ __launch_bounds__(256)
void cvt_weights(const float* __restrict__ s0, const float* __restrict__ s1,
                 const float* __restrict__ s2, const float* __restrict__ s3,
                 const float* __restrict__ s4, const float* __restrict__ s5,
                 const float* __restrict__ s6, const float* __restrict__ s7)
{
    int i = (blockIdx.x * 256 + threadIdx.x) * 4;
    if (i >= W_TOTAL) return;
    const float* src; int off;
    if      (i < OFF_WHH1)   { src = s0; off = OFF_WIH1; }
    else if (i < OFF_WSELF1) { src = s1; off = OFF_WHH1; }
    else if (i < OFF_WNEIGH1){ src = s2; off = OFF_WSELF1; }
    else if (i < OFF_WIH2)   { src = s3; off = OFF_WNEIGH1; }
    else if (i < OFF_WHH2)   { src = s4; off = OFF_WIH2; }
    else if (i < OFF_WSELF2) { src = s5; off = OFF_WHH2; }
    else if (i < OFF_WNEIGH2){ src = s6; off = OFF_WSELF2; }
    else                     { src = s7; off = OFF_WNEIGH2; }
    float4 v = *reinterpret_cast<const float4*>(src + (i - off));
    bf16_t o[4] __attribute__((aligned(8)));
    o[0] = (bf16_t)v.x; o[1] = (bf16_t)v.y; o[2] = (bf16_t)v.z; o[3] = (bf16_t)v.w;
    *reinterpret_cast<uint2*>(&g_wbuf[i]) = *reinterpret_cast<const uint2*>(o);
}

// counting sort of node ids by DESCENDING degree (LPT block scheduling).
__global__ __launch_bounds__(256)
void build_perm(const int* __restrict__ deg, int* __restrict__ perm)
{
    __shared__ int s_base[DMAXX + 1];
    const int tid = threadIdx.x;
    if (tid <= DMAXX) s_base[tid] = 0;
    __syncthreads();
    for (int i = tid; i < NN; i += 256) {
        int d = deg[i]; d = d < 0 ? 0 : (d > DMAXX ? DMAXX : d);
        atomicAdd(&s_base[d], 1);
    }
    __syncthreads();
    if (tid == 0) {
        int acc = 0;
        for (int d = DMAXX; d >= 0; --d) { int c = s_base[d]; s_base[d] = acc; acc += c; }
    }
    __syncthreads();
    for (int i = tid; i < NN; i += 256) {
        int d = deg[i]; d = d < 0 ? 0 : (d > DMAXX ? DMAXX : d);
        int p = atomicAdd(&s_base[d], 1);
        perm[p] = i;
    }
}

__device__ __forceinline__ float fsig(float x) { return 1.0f / (1.0f + __expf(-x)); }
__device__ __forceinline__ float ftanh(float x) { return 1.0f - 2.0f / (__expf(2.0f * x) + 1.0f); }
__device__ __forceinline__ float bf2f(unsigned short s) {
    union { unsigned u; float f; } v; v.u = ((unsigned)s) << 16; return v.f;
}

// 8-byte system-scope load: bypasses L1+L2 (L2 = agent coherence point),
// served by memory-side Infinity Cache. Keeps zero-reuse gather lines from
// evicting the L2-resident weights.
__device__ __forceinline__ u16x4 ldg_sys(const bf16_t* p) {
    u64_t raw = __hip_atomic_load(reinterpret_cast<const u64_t*>(p),
                                  __ATOMIC_RELAXED, __HIP_MEMORY_SCOPE_SYSTEM);
    union { u64_t u; u16x4 v; } cv; cv.u = raw; return cv.v;
}

// stage a 64-row x-tile (linear rows, row-clamped) into LDS as bf16
template<int F, int LDA, int NT, bool XF32>
__device__ __forceinline__ void stage_tile(bf16_t* dst, const void* src, int row0, int tid)
{
    constexpr int UN = F / 8;          // 16B(bf16) units per row
    for (int e = tid; e < 64 * UN; e += NT) {
        int m = e / UN, sub = e - m * UN;
        int row = row0 + m; if (row >= NN) row = NN - 1;
        if constexpr (XF32) {
            const float* p = (const float*)src + (size_t)row * F + sub * 8;
            float4 f0 = reinterpret_cast<const float4*>(p)[0];
            float4 f1 = reinterpret_cast<const float4*>(p)[1];
            bf16_t t[8] __attribute__((aligned(16)));
            t[0]=(bf16_t)f0.x; t[1]=(bf16_t)f0.y; t[2]=(bf16_t)f0.z; t[3]=(bf16_t)f0.w;
            t[4]=(bf16_t)f1.x; t[5]=(bf16_t)f1.y; t[6]=(bf16_t)f1.z; t[7]=(bf16_t)f1.w;
            *reinterpret_cast<uint4*>(&dst[m * LDA + sub * 8]) = *reinterpret_cast<const uint4*>(t);
        } else {
            const bf16_t* p = (const bf16_t*)src + (size_t)row * F + sub * 8;
            *reinterpret_cast<uint4*>(&dst[m * LDA + sub * 8]) = *reinterpret_cast<const uint4*>(p);
        }
    }
}

// stage a 64-row x-tile with per-row node ids (from LDS array) into LDS
template<int F, int LDA, int NT, bool XF32>
__device__ __forceinline__ void stage_rows(bf16_t* dst, const void* src, const int* nodes, int tid)
{
    constexpr int UN = F / 8;
    for (int e = tid; e < 64 * UN; e += NT) {
        int m = e / UN, sub = e - m * UN;
        int row = nodes[m];
        if constexpr (XF32) {
            const float* p = (const float*)src + (size_t)row * F + sub * 8;
            float4 f0 = reinterpret_cast<const float4*>(p)[0];
            float4 f1 = reinterpret_cast<const float4*>(p)[1];
            bf16_t t[8] __attribute__((aligned(16)));
            t[0]=(bf16_t)f0.x; t[1]=(bf16_t)f0.y; t[2]=(bf16_t)f0.z; t[3]=(bf16_t)f0.w;
            t[4]=(bf16_t)f1.x; t[5]=(bf16_t)f1.y; t[6]=(bf16_t)f1.z; t[7]=(bf16_t)f1.w;
            *reinterpret_cast<uint4*>(&dst[m * LDA + sub * 8]) = *reinterpret_cast<const uint4*>(t);
        } else {
            const bf16_t* p = (const bf16_t*)src + (size_t)row * F + sub * 8;
            *reinterpret_cast<uint4*>(&dst[m * LDA + sub * 8]) = *reinterpret_cast<const uint4*>(p);
        }
    }
}

// xg[N, 4F] (gate-interleaved [c][g]) = x[N,F] @ W[4F,F]^T + b0 + b1
template<int F, int G, int NW, bool XF32>
__global__ __launch_bounds__(NW * 64, 2)
void xg_gemm(const void* __restrict__ xsrc_v, const bf16_t* __restrict__ W,
             const float* __restrict__ b0, const float* __restrict__ b1v,
             bf16_t* __restrict__ xg)
{
    constexpr int LDA = F + 8, KK = F / 32, NT = NW * 64;
    constexpr int CPW = G / NW;        // linear out-cols per wave
    constexpr int CT = CPW / 16;
    static_assert(CPW % 16 == 0 && F % 16 == 0, "");
    const int tid = threadIdx.x, wave = tid >> 6, lane = tid & 63;
    const int q = lane >> 4, m16 = lane & 15;
    const int row0 = blockIdx.x * 64;

    __shared__ __align__(16) bf16_t s_x[64 * LDA];
    stage_tile<F, LDA, NT, XF32>(s_x, xsrc_v, row0, tid);
    __syncthreads();

    #pragma unroll
    for (int ct = 0; ct < CT; ++ct) {
        const int lc0 = wave * CPW + ct * 16;   // linear col block (within one gate)
        const int g = lc0 / F, c0 = lc0 - g * F;
        const float bias = b0[lc0 + m16] + b1v[lc0 + m16];
        f32x4 acc[4];
        #pragma unroll
        for (int rt = 0; rt < 4; ++rt)
            #pragma unroll
            for (int r = 0; r < 4; ++r) acc[rt][r] = bias;
        #pragma unroll
        for (int kk = 0; kk < KK; ++kk) {
            const int ko = kk * 32 + q * 8;
            bf16x8 b = *reinterpret_cast<const bf16x8*>(W + (size_t)(lc0 + m16) * F + ko);
            #pragma unroll
            for (int rt = 0; rt < 4; ++rt) {
                bf16x8 a = *reinterpret_cast<const bf16x8*>(&s_x[(rt * 16 + m16) * LDA + ko]);
                acc[rt] = __builtin_amdgcn_mfma_f32_16x16x32_bf16(a, b, acc[rt], 0, 0, 0);
            }
        }
        #pragma unroll
        for (int rt = 0; rt < 4; ++rt)
            #pragma unroll
            for (int r = 0; r < 4; ++r) {
                int row = row0 + rt * 16 + q * 4 + r;
                if (row < NN)
                    xg[(size_t)row * G + (size_t)(c0 + m16) * 4 + g] = (bf16_t)acc[rt][r];
            }
    }
}

// LSTM recurrence over gathered neighbors + fused fc epilogue.
// Block b: nodes perm[b*64 .. b*64+63] (degree-sorted DESC), loops to
// tmax = max(deg in block). 16 waves = NWR row-groups x NWC col-waves.
// Each step runs NPASS sequential passes of 2 row-tiles (spill-free).
// gates = gather(xg, system-scope) + h @ Whh^T ;
// out = x_self@Wself^T + h_fin@Wneigh^T + b
template<int F, int OUTF, bool RELU, bool XF32, typename OutT>
__global__ __launch_bounds__(1024, 4)
void sage_rec(const void* __restrict__ xself_v,
              const bf16_t* __restrict__ xg,
              const int* __restrict__ nbr_idx, const int* __restrict__ deg,
              const int* __restrict__ perm,
              const bf16_t* __restrict__ Whh,
              const bf16_t* __restrict__ Wself, const bf16_t* __restrict__ Wneigh,
              const float* __restrict__ bout, OutT* __restrict__ outp)
{
    constexpr int M = 64, LDA = F + 8, KK = F / 32, NW = 16, NT = 1024;
    constexpr int NWC = F / 16;            // col-waves, 16 cols each
    constexpr int NWR = NW / NWC;          // row-groups (1 for F=256, 2 for F=128)
    constexpr int RT = M / (16 * NWR);     // row-tiles per wave (4 or 2)
    constexpr int NPASS = RT / 2;          // 2 row-tiles per pass
    constexpr int G4 = 4 * F;
    static_assert(NWC * NWR == NW && RT % 2 == 0, "");
    const int tid = threadIdx.x, wave = tid >> 6, lane = tid & 63;
    const int q = lane >> 4, m16 = lane & 15;
    const int wc = wave % NWC, wr = wave / NWC;
    const int ROWB = wr * (RT * 16);       // this wave's row base in tile
    const int col = wc * 16 + m16;         // this lane's output column (per gate)
    const int slot0 = blockIdx.x * M;

    __shared__ __align__(16) bf16_t s_h[2][M * LDA];   // double-buffered h
    __shared__ int s_idx[M * DMAXX];
    __shared__ int s_deg[M];
    __shared__ int s_node[M];
    __shared__ int s_tmax;

    for (int i = tid; i < M; i += NT) {
        int slot = slot0 + i; if (slot >= NN) slot = NN - 1;
        int node = perm[slot];
        s_node[i] = node;
        s_deg[i] = deg[node];
    }
    __syncthreads();
    for (int i = tid; i < M * DMAXX; i += NT) {
        int node = s_node[i >> 4];
        int v = nbr_idx[node * DMAXX + (i & 15)];
        if (v < 0) v = 0; if (v >= NN) v = NN - 1;
        s_idx[i] = v;
    }
    for (int i = tid; i < M * LDA; i += NT) s_h[0][i] = (bf16_t)0.0f;
    if (tid == 0) {
        int mx = 1;
        for (int i = 0; i < M; ++i) { int d = s_deg[i]; mx = d > mx ? d : mx; }
        s_tmax = mx;
    }
    __syncthreads();
    const int tmax = s_tmax;   // uniform-degree blocks: ~= block's degree bucket

    // persistent cell state: one f32x4 per row-tile (named, never runtime-indexed)
    f32x4 c0, c1, c2, c3;
    #pragma unroll
    for (int r = 0; r < 4; ++r) { c0[r]=0.f; c1[r]=0.f; c2[r]=0.f; c3[r]=0.f; }

    // one pass: 2 row-tiles (rtb, rtb+1) x all 4 gates for this wave's 16 cols
    auto do_pass = [&](int rtb, f32x4& cA, f32x4& cB,
                       const bf16_t* cur, bf16_t* nxt, int t) {
        // gather gate-init (xg = x@Wih^T + biases), 8B/elem, SYSTEM SCOPE
        // (bypasses L2 -> weights stay resident there)
        u16x4 u[2][4];
        #pragma unroll
        for (int j = 0; j < 2; ++j)
            #pragma unroll
            for (int r = 0; r < 4; ++r) {
                int row = s_idx[(ROWB + (rtb + j) * 16 + q * 4 + r) * DMAXX + t];
                u[j][r] = ldg_sys(xg + (size_t)row * G4 + (size_t)col * 4);
            }
        f32x4 acc[2][4];
        #pragma unroll
        for (int j = 0; j < 2; ++j)
            #pragma unroll
            for (int g = 0; g < 4; ++g)
                #pragma unroll
                for (int r = 0; r < 4; ++r) acc[j][g][r] = 0.0f;
        #pragma unroll
        for (int kk = 0; kk < KK; ++kk) {
            const int ko = kk * 32 + q * 8;
            bf16x8 ah0 = *reinterpret_cast<const bf16x8*>(
                &cur[(ROWB + rtb * 16 + m16) * LDA + ko]);
            bf16x8 ah1 = *reinterpret_cast<const bf16x8*>(
                &cur[(ROWB + (rtb + 1) * 16 + m16) * LDA + ko]);
            #pragma unroll
            for (int g = 0; g < 4; ++g) {
                bf16x8 bh = *reinterpret_cast<const bf16x8*>(
                    Whh + (size_t)(g * F + col) * F + ko);
                acc[0][g] = __builtin_amdgcn_mfma_f32_16x16x32_bf16(ah0, bh, acc[0][g], 0, 0, 0);
                acc[1][g] = __builtin_amdgcn_mfma_f32_16x16x32_bf16(ah1, bh, acc[1][g], 0, 0, 0);
            }
        }
        // pointwise LSTM update + masked store:
        //   t <  deg : write h_new (and update c)
        //   t == deg : copy frozen h from cur (this thread's t-1 write)
        //   t >  deg : skip -- nxt already holds the frozen value
        #pragma unroll
        for (int j = 0; j < 2; ++j) {
            f32x4& cc = j ? cB : cA;
            #pragma unroll
            for (int r = 0; r < 4; ++r) {
                int rowr = ROWB + (rtb + j) * 16 + q * 4 + r;
                float iv = fsig (acc[j][0][r] + bf2f(u[j][r].x));
                float fv = fsig (acc[j][1][r] + bf2f(u[j][r].y));
                float gv = ftanh(acc[j][2][r] + bf2f(u[j][r].z));
                float ov = fsig (acc[j][3][r] + bf2f(u[j][r].w));
                float cn = fv * cc[r] + iv * gv;
                float hv = ov * ftanh(cn);
                const int pos = rowr * LDA + col;
                int d = s_deg[rowr];
                if (t < d) {
                    cc[r] = cn;
                    nxt[pos] = (bf16_t)hv;
                } else if (t == d) {
                    reinterpret_cast<unsigned short*>(nxt)[pos] =
                        reinterpret_cast<const unsigned short*>(cur)[pos];
                }
            }
        }
    };

    #pragma unroll 1
    for (int t = 0; t < tmax; ++t) {
        const bf16_t* cur = s_h[t & 1];
        bf16_t* nxt = s_h[(t + 1) & 1];
        do_pass(0, c0, c1, cur, nxt, t);
        if constexpr (NPASS > 1) {
            __builtin_amdgcn_sched_barrier(0);   // keep passes sequential (reg pressure)
            do_pass(2, c2, c3, cur, nxt, t);
        }
        __syncthreads();   // nxt fully written; cur fully consumed
    }

    // final h is in s_h[tmax&1]; stage self-rows into the other buffer
    const int fb = tmax & 1;
    const bf16_t* hfin = s_h[fb];
    bf16_t* hstage = s_h[fb ^ 1];
    stage_rows<F, LDA, NT, XF32>(hstage, xself_v, s_node, tid);
    __syncthreads();

    // epilogue: out = x_self @ Wself^T + h_fin @ Wneigh^T + bout (+relu)
    constexpr int NCT = OUTF / 16;
    constexpr int TILES = NCT * 4;     // 4 row-tiles of the 64-node tile
    constexpr int TPW = TILES / NW;
    static_assert(TILES % NW == 0, "");
    #pragma unroll
    for (int tt = 0; tt < TPW; ++tt) {
        int tile = wave * TPW + tt;
        int ot = tile % NCT, rt = tile / NCT;
        f32x4 o;
        o[0] = 0.f; o[1] = 0.f; o[2] = 0.f; o[3] = 0.f;
        #pragma unroll
        for (int kk = 0; kk < KK; ++kk) {
            const int ko = kk * 32 + q * 8;
            bf16x8 axs = *reinterpret_cast<const bf16x8*>(&hstage[(rt * 16 + m16) * LDA + ko]);
            bf16x8 am  = *reinterpret_cast<const bf16x8*>(&hfin[(rt * 16 + m16) * LDA + ko]);
            bf16x8 bs = *reinterpret_cast<const bf16x8*>(Wself  + (size_t)(ot * 16 + m16) * F + ko);
            bf16x8 bn = *reinterpret_cast<const bf16x8*>(Wneigh + (size_t)(ot * 16 + m16) * F + ko);
            o = __builtin_amdgcn_mfma_f32_16x16x32_bf16(axs, bs, o, 0, 0, 0);
            o = __builtin_amdgcn_mfma_f32_16x16x32_bf16(am,  bn, o, 0, 0, 0);
        }
        int ocol = ot * 16 + m16;
        float bias = bout[ocol];
        #pragma unroll
        for (int r = 0; r < 4; ++r) {
            int node = s_node[rt * 16 + q * 4 + r];
            float v = o[r] + bias;
            if (RELU) v = fmaxf(v, 0.0f);
            outp[(size_t)node * OUTF + ocol] = (OutT)v;
        }
    }
}

extern "C" void kernel_launch(void* const* d_in, const int* in_sizes, int n_in,
                              void* d_out, int out_size, void* d_ws, size_t ws_size,
                              hipStream_t stream)
{
    const float* feat    = (const float*)d_in[0];
    const int*   nbr     = (const int*)d_in[1];
    const int*   degp    = (const int*)d_in[2];
    const float* Wih1    = (const float*)d_in[3];
    const float* Whh1    = (const float*)d_in[4];
    const float* bih1    = (const float*)d_in[5];
    const float* bhh1    = (const float*)d_in[6];
    const float* Wself1  = (const float*)d_in[7];
    const float* Wneigh1 = (const float*)d_in[8];
    const float* b1      = (const float*)d_in[9];
    const float* Wih2    = (const float*)d_in[10];
    const float* Whh2    = (const float*)d_in[11];
    const float* bih2    = (const float*)d_in[12];
    const float* bhh2    = (const float*)d_in[13];
    const float* Wself2  = (const float*)d_in[14];
    const float* Wneigh2 = (const float*)d_in[15];
    const float* b2      = (const float*)d_in[16];

    bf16_t *hglob, *wglob, *xg1, *xg2;
    int *permg;
    hipGetSymbolAddress((void**)&hglob, HIP_SYMBOL(g_hbuf));
    hipGetSymbolAddress((void**)&wglob, HIP_SYMBOL(g_wbuf));
    hipGetSymbolAddress((void**)&xg1,   HIP_SYMBOL(g_xg1));
    hipGetSymbolAddress((void**)&xg2,   HIP_SYMBOL(g_xg2));
    hipGetSymbolAddress((void**)&permg, HIP_SYMBOL(g_perm));

    cvt_weights<<<W_TOTAL / 4 / 256, 256, 0, stream>>>(
        Wih1, Whh1, Wself1, Wneigh1, Wih2, Whh2, Wself2, Wneigh2);

    build_perm<<<1, 256, 0, stream>>>(degp, permg);

    const int grid = (NN + 63) / 64;   // 469 WGs

    xg_gemm<128, 512, 8, true><<<grid, 512, 0, stream>>>(
        feat, wglob + OFF_WIH1, bih1, bhh1, xg1);

    sage_rec<128, 256, true, true, bf16_t><<<grid, 1024, 0, stream>>>(
        feat, xg1, nbr, degp, permg, wglob + OFF_WHH1,
        wglob + OFF_WSELF1, wglob + OFF_WNEIGH1, b1, hglob);

    xg_gemm<256, 1024, 8, false><<<grid, 512, 0, stream>>>(
        hglob, wglob + OFF_WIH2, bih2, bhh2, xg2);

    sage_rec<256, 64, false, false, float><<<grid, 1024, 0, stream>>>(
        hglob, xg2, nbr, degp, permg, wglob + OFF_WHH2,
        wglob + OFF_WSELF2, wglob + OFF_WNEIGH2, b2, (float*)d_out);
}